// Round 11
// baseline (452.045 us; speedup 1.0000x reference)
//
#include <hip/hip_runtime.h>
#include <hip/hip_bf16.h>
#include <cstddef>
#include <cstdint>

#define N_NODES 100000
#define N_ROWS  100032            // padded to 32-row tiles
#define DUMMY   100000            // zeroed pad row in feature buffers
#define N_EDGES 1600000
#define N_REL   4
#define N_BASES 30
#define FIN     86
#define HID     128
#define N_CLS   18
#define N_GRAPH 512
#define KCAT    640               // 4 relation blocks + root block, 128 each
#define BM      32                // rows per fused block / per tile
#define NKK     (KCAT / 32)       // 20 K-steps

#define NTILE   (N_ROWS / BM)     // 3126 tiles
#define NTILEP  3200              // padded allocation
#define TPAD    (3 * 128)         // max 4-pad slack per tile (128 segments * 3)
#define SEGP    (NTILE * 128)     // 400128 (node*4+r table)
#define SSRC_ALLOC (N_EDGES + NTILE * (TPAD + 4) + 64)

typedef __attribute__((ext_vector_type(8))) short bf16x8;
typedef __attribute__((ext_vector_type(4))) float f32x4;

__device__ inline float blo(unsigned int u) {
    union { unsigned int i; float f; } c; c.i = u << 16; return c.f;
}
__device__ inline float bhi(unsigned int u) {
    union { unsigned int i; float f; } c; c.i = u & 0xffff0000u; return c.f;
}
__device__ inline unsigned short f2bf(float f) {
    __hip_bfloat16 h = __float2bfloat16(f);
    return *reinterpret_cast<unsigned short*>(&h);
}
__device__ inline unsigned int pk2(float lo, float hi) {
    return (unsigned int)f2bf(lo) | ((unsigned int)f2bf(hi) << 16);
}

// ===== fused preprocessing: xcvt + wt1 + wt2 + zero(tilecnt, g) =====
#define PREP_R0 (N_ROWS * HID)            // xcvt + H1 pad-row zero
#define PREP_R1 (KCAT * HID)              // wt1
#define PREP_R2 (KCAT * HID)              // wt2
#define PREP_R3 NTILEP                    // tilecnt zero
#define PREP_R4 (N_GRAPH * HID)           // g zero
#define PREP_TOTAL (PREP_R0 + PREP_R1 + PREP_R2 + PREP_R3 + PREP_R4)

__device__ inline void wt_body(int id, int KV, const float* __restrict__ basis,
                               const float* __restrict__ comp, const float* __restrict__ root,
                               short* __restrict__ Wt) {
    int n = id & 127, s = id >> 7;
    int k = s & 127, blk = s >> 7;
    float v = 0.f;
    if (k < KV) {
        if (blk < N_REL) {
            for (int b = 0; b < N_BASES; ++b)
                v += comp[blk * N_BASES + b] * basis[((size_t)b * KV + k) * HID + n];
        } else {
            v = root[k * HID + n];
        }
    }
    Wt[(size_t)n * KCAT + s] = (short)f2bf(v);
}

__global__ void k_prep(const float* __restrict__ x,
                       const float* __restrict__ basis1, const float* __restrict__ comp1,
                       const float* __restrict__ root1,
                       const float* __restrict__ basis2, const float* __restrict__ comp2,
                       const float* __restrict__ root2,
                       short* __restrict__ X0, short* __restrict__ H1,
                       short* __restrict__ Wt1, short* __restrict__ Wt2,
                       int* __restrict__ tilecnt, float* __restrict__ g) {
    int id = blockIdx.x * 256 + threadIdx.x;
    if (id < PREP_R0) {
        int n = id >> 7, k = id & 127;
        float v = (n < N_NODES && k < FIN) ? x[n * FIN + k] : 0.f;
        X0[id] = (short)f2bf(v);
        if (n >= N_NODES) H1[id] = 0;
        return;
    }
    id -= PREP_R0;
    if (id < PREP_R1) { wt_body(id, FIN, basis1, comp1, root1, Wt1); return; }
    id -= PREP_R1;
    if (id < PREP_R2) { wt_body(id, HID, basis2, comp2, root2, Wt2); return; }
    id -= PREP_R2;
    if (id < PREP_R3) { tilecnt[id] = 0; return; }
    id -= PREP_R3;
    if (id < PREP_R4) g[id] = 0.f;
}

// per-tile histogram + per-edge rank (3126 hot counters)
__global__ void k_tilecnt(const int* __restrict__ dst, int* __restrict__ tilecnt,
                          int* __restrict__ rank) {
    int e = blockIdx.x * 256 + threadIdx.x;
    if (e >= N_EDGES) return;
    rank[e] = atomicAdd(tilecnt + (dst[e] >> 5), 1);
}

// one-block exclusive scans: rawoff (input regions, raw counts) and
// obase (output regions, capacity pad4(n)+TPAD -> always 4-aligned)
__global__ void k_tilescan(const int* __restrict__ tilecnt, int* __restrict__ rawoff,
                           int* __restrict__ obase) {
    __shared__ int s1[1024], s2[1024];
    int t = threadIdx.x;
    int base = t * 4;
    int v[4], w[4], sum1 = 0, sum2 = 0;
#pragma unroll
    for (int j = 0; j < 4; ++j) {
        v[j] = (base + j < NTILE) ? tilecnt[base + j] : 0;
        w[j] = ((v[j] + 3) & ~3) + TPAD;
        sum1 += v[j]; sum2 += w[j];
    }
    s1[t] = sum1; s2[t] = sum2;
    __syncthreads();
    for (int d = 1; d < 1024; d <<= 1) {
        int a1 = (t >= d) ? s1[t - d] : 0;
        int a2 = (t >= d) ? s2[t - d] : 0;
        __syncthreads();
        s1[t] += a1; s2[t] += a2;
        __syncthreads();
    }
    int p1 = s1[t] - sum1, p2 = s2[t] - sum2;
#pragma unroll
    for (int j = 0; j < 4; ++j) {
        if (base + j < NTILE) {
            rawoff[base + j] = p1;
            obase[base + j] = p2;
            p1 += v[j]; p2 += w[j];
        }
    }
}

// scatter (src, key) into per-tile regions (~4KB each, line-friendly)
__global__ void k_tilescatter(const int* __restrict__ et, const int* __restrict__ srcI,
                              const int* __restrict__ dstI, const int* __restrict__ rank,
                              const int* __restrict__ rawoff, int2* __restrict__ ebuf) {
    int e = blockIdx.x * 256 + threadIdx.x;
    if (e >= N_EDGES) return;
    int d = dstI[e];
    int t = d >> 5;
    int key = ((d & 31) << 2) | et[e];
    int2 rec; rec.x = srcI[e]; rec.y = key;
    ebuf[rawoff[t] + rank[e]] = rec;
}

// per-tile LDS counting sort -> 4-padded CSR (4-aligned bins) + off/cnt tables
__global__ void k_tilesort(const int2* __restrict__ ebuf, const int* __restrict__ tilecnt,
                           const int* __restrict__ rawoff, const int* __restrict__ obase,
                           int* __restrict__ ssrc, int* __restrict__ off,
                           int* __restrict__ cnt) {
    __shared__ int hist[128], boff[128], cur[128];
    const int t = blockIdx.x, tid = threadIdx.x;
    const int n = tilecnt[t];
    const int base_in = rawoff[t];
    const int base_out = obase[t];              // 4-aligned by construction
    if (tid < 128) { hist[tid] = 0; cur[tid] = 0; }
    __syncthreads();
    for (int i = tid; i < n; i += 256)
        atomicAdd(&hist[ebuf[base_in + i].y], 1);
    __syncthreads();
    if (tid == 0) {
        int run = 0;
        for (int b = 0; b < 128; ++b) { boff[b] = run; run += (hist[b] + 3) & ~3; }
    }
    __syncthreads();
    for (int i = tid; i < n; i += 256) {
        int2 e = ebuf[base_in + i];
        int p = atomicAdd(&cur[e.y], 1);
        ssrc[base_out + boff[e.y] + p] = e.x;
    }
    if (tid < 128) {
        int b = tid, h = hist[b], bo = base_out + boff[b];
        int hp = (h + 3) & ~3;
        for (int j = h; j < hp; ++j) ssrc[bo + j] = DUMMY;
        off[t * 128 + b] = bo;                  // == off[node*4 + r]
        cnt[t * 128 + b] = h;
    }
}

// ---- single-relation gather+mean into swizzled LDS A-tile (round-8 core) ----
__device__ __forceinline__ void agg_one(const short* __restrict__ F,
                                        const int4* __restrict__ sp,
                                        int o, int c, int4 e4,
                                        char* Ab, int G, int q, int r) {
    float a[8];
#pragma unroll
    for (int j = 0; j < 8; ++j) a[j] = 0.f;
    const int cq = q * 8;
    const int nch = (c + 3) >> 2;
    const int ib = o >> 2;                      // o is 4-aligned
    for (int ch = 0; ch < nch; ++ch) {
        if (ch) e4 = sp[ib + ch];
        uint4 v0 = *reinterpret_cast<const uint4*>(F + (size_t)e4.x * HID + cq);
        uint4 v1 = *reinterpret_cast<const uint4*>(F + (size_t)e4.y * HID + cq);
        uint4 v2 = *reinterpret_cast<const uint4*>(F + (size_t)e4.z * HID + cq);
        uint4 v3 = *reinterpret_cast<const uint4*>(F + (size_t)e4.w * HID + cq);
        a[0] += blo(v0.x); a[1] += bhi(v0.x); a[2] += blo(v0.y); a[3] += bhi(v0.y);
        a[4] += blo(v0.z); a[5] += bhi(v0.z); a[6] += blo(v0.w); a[7] += bhi(v0.w);
        a[0] += blo(v1.x); a[1] += bhi(v1.x); a[2] += blo(v1.y); a[3] += bhi(v1.y);
        a[4] += blo(v1.z); a[5] += bhi(v1.z); a[6] += blo(v1.w); a[7] += bhi(v1.w);
        a[0] += blo(v2.x); a[1] += bhi(v2.x); a[2] += blo(v2.y); a[3] += bhi(v2.y);
        a[4] += blo(v2.z); a[5] += bhi(v2.z); a[6] += blo(v2.w); a[7] += bhi(v2.w);
        a[0] += blo(v3.x); a[1] += bhi(v3.x); a[2] += blo(v3.y); a[3] += bhi(v3.y);
        a[4] += blo(v3.z); a[5] += bhi(v3.z); a[6] += blo(v3.w); a[7] += bhi(v3.w);
    }
    const float inv = (c > 0) ? 1.f / (float)c : 0.f;
    uint4 w;
    w.x = pk2(a[0] * inv, a[1] * inv);
    w.y = pk2(a[2] * inv, a[3] * inv);
    w.z = pk2(a[4] * inv, a[5] * inv);
    w.w = pk2(a[6] * inv, a[7] * inv);
    const int swz = (G & 7) << 4;
    *reinterpret_cast<uint4*>(Ab + (G * 1280 + ((r * 256 + q * 16) ^ swz))) = w;
}

// ===== fused agg+GEMM: one 32-row M-tile per block, 512 thr (8 waves) =====
template <int MODE>
__launch_bounds__(512, 4)
__global__ void k_fused(const short* __restrict__ F,
                        const int* __restrict__ off, const int* __restrict__ cnt,
                        const int* __restrict__ ssrc,
                        const short* __restrict__ Wt,
                        const float* __restrict__ bias,
                        short* __restrict__ H,
                        const int* __restrict__ batch, float* __restrict__ g) {
    __shared__ short As[BM * KCAT];                 // 40960 B
    char* Ab = reinterpret_cast<char*>(As);
    const int tid = threadIdx.x;
    const int m0 = blockIdx.x * BM;
    const int G = tid >> 4, q = tid & 15;
    const int node = m0 + G;

    // hoisted segment descriptors + chunk-0 prefetch (r0, r1)
    int4 o4 = (int4){0, 0, 0, 0}, c4 = (int4){0, 0, 0, 0};
    const int4* sp = reinterpret_cast<const int4*>(ssrc);
    if (node < N_NODES) {
        o4 = *reinterpret_cast<const int4*>(off + node * 4);
        c4 = *reinterpret_cast<const int4*>(cnt + node * 4);
    }
    int4 pre0 = sp[o4.x >> 2];
    int4 pre1 = sp[o4.y >> 2];

    // ---- phase 1: root block cols [512,640)
    {
        uint4 v = *reinterpret_cast<const uint4*>(F + (size_t)(m0 + G) * HID + q * 8);
        const int p = (G * 1280 + 1024 + q * 16) ^ ((G & 7) << 4);
        *reinterpret_cast<uint4*>(Ab + p) = v;
    }

    // ---- phase 2: relation means cols [0,512)
    if (node < N_NODES) {
        agg_one(F, sp, o4.x, c4.x, pre0, Ab, G, q, 0);
        agg_one(F, sp, o4.y, c4.y, pre1, Ab, G, q, 1);
        agg_one(F, sp, o4.z, c4.z, sp[o4.z >> 2], Ab, G, q, 2);
        agg_one(F, sp, o4.w, c4.w, sp[o4.w >> 2], Ab, G, q, 3);
    }
    __syncthreads();

    // ---- phase 3: MFMA over K=640 (B slice streamed from L2)
    const int wave = tid >> 6, lane = tid & 63;
    const int ql = lane & 15, hi = lane >> 4;
    const int col = wave * 16 + ql;

    bf16x8 bfrag[NKK];
    {
        const short* bp = Wt + (size_t)col * KCAT + hi * 8;
#pragma unroll
        for (int kk = 0; kk < NKK; ++kk)
            bfrag[kk] = *reinterpret_cast<const bf16x8*>(bp + kk * 32);
    }

    f32x4 acc[2];
    acc[0] = (f32x4){0.f, 0.f, 0.f, 0.f};
    acc[1] = (f32x4){0.f, 0.f, 0.f, 0.f};
    const int arow = ql * 1280;
    const int bx = (hi * 16) ^ ((ql & 7) << 4);
#pragma unroll
    for (int kk = 0; kk < NKK; ++kk) {
        const int bo = (kk * 64) ^ bx;
#pragma unroll
        for (int rf = 0; rf < 2; ++rf) {
            bf16x8 a = *reinterpret_cast<const bf16x8*>(Ab + arow + rf * (16 * 1280) + bo);
            acc[rf] = __builtin_amdgcn_mfma_f32_16x16x32_bf16(a, bfrag[kk], acc[rf], 0, 0, 0);
        }
    }

    // ---- epilogue
    if (MODE == 1) {
        const float bc = bias[col];
#pragma unroll
        for (int rf = 0; rf < 2; ++rf) {
#pragma unroll
            for (int r = 0; r < 4; ++r) {
                const int row = m0 + rf * 16 + hi * 4 + r;
                if (row < N_NODES) {
                    float v = fmaxf(acc[rf][r] + bc, 0.f);
                    H[(size_t)row * HID + col] = (short)f2bf(v);
                }
            }
        }
    } else {
        int curb = -1;
        float run = 0.f;
#pragma unroll
        for (int rf = 0; rf < 2; ++rf) {
#pragma unroll
            for (int r = 0; r < 4; ++r) {
                const int row = m0 + rf * 16 + hi * 4 + r;
                if (row < N_NODES) {
                    int b = batch[row];
                    if (b != curb) {
                        if (curb >= 0) atomicAdd(&g[curb * HID + col], run);
                        curb = b; run = 0.f;
                    }
                    run += acc[rf][r];
                }
            }
        }
        if (curb >= 0) atomicAdd(&g[curb * HID + col], run);
    }
}

// per-graph: pooled = g + cnt*bias2; relu(pooled @ fc_w + fc_b) -> log_softmax
__global__ void k_fc(const float* __restrict__ g, const float* __restrict__ bias2,
                     const int* __restrict__ batch, const float* __restrict__ fcw,
                     const float* __restrict__ fcb, float* __restrict__ out) {
    __shared__ float pooled[HID];
    __shared__ float vals[N_CLS];
    __shared__ float s_lse;
    __shared__ int s_cnt;
    int gi = blockIdx.x, t = threadIdx.x;
    if (t == 0) {
        int lo = 0, hi = N_NODES;
        while (lo < hi) { int m = (lo + hi) >> 1; if (batch[m] < gi) lo = m + 1; else hi = m; }
        int lo2 = lo, hi2 = N_NODES;
        while (lo2 < hi2) { int m = (lo2 + hi2) >> 1; if (batch[m] < gi + 1) lo2 = m + 1; else hi2 = m; }
        s_cnt = lo2 - lo;
    }
    __syncthreads();
    pooled[t] = g[gi * HID + t] + (float)s_cnt * bias2[t];
    __syncthreads();
    if (t < N_CLS) {
        float acc = fcb[t];
        for (int k = 0; k < HID; k++) acc = fmaf(pooled[k], fcw[k * N_CLS + t], acc);
        vals[t] = fmaxf(acc, 0.f);
    }
    __syncthreads();
    if (t == 0) {
        float m = vals[0];
        for (int c = 1; c < N_CLS; c++) m = fmaxf(m, vals[c]);
        float ssum = 0.f;
        for (int c = 0; c < N_CLS; c++) ssum += expf(vals[c] - m);
        s_lse = m + logf(ssum);
    }
    __syncthreads();
    if (t < N_CLS) out[gi * N_CLS + t] = vals[t] - s_lse;
}

extern "C" void kernel_launch(void* const* d_in, const int* in_sizes, int n_in,
                              void* d_out, int out_size, void* d_ws, size_t ws_size,
                              hipStream_t stream) {
    const float* x      = (const float*)d_in[0];
    const int*   ei     = (const int*)d_in[1];
    const int*   src    = ei;
    const int*   dst    = ei + N_EDGES;
    const int*   et     = (const int*)d_in[2];
    const int*   batch  = (const int*)d_in[3];
    const float* basis1 = (const float*)d_in[4];
    const float* comp1  = (const float*)d_in[5];
    const float* root1  = (const float*)d_in[6];
    const float* bias1  = (const float*)d_in[7];
    const float* basis2 = (const float*)d_in[8];
    const float* comp2  = (const float*)d_in[9];
    const float* root2  = (const float*)d_in[10];
    const float* bias2  = (const float*)d_in[11];
    const float* fcw    = (const float*)d_in[12];
    const float* fcb    = (const float*)d_in[13];
    float* out = (float*)d_out;

    // workspace layout (~88 MB), 16B-aligned sections
    short* X0      = (short*)d_ws;                     // [N_ROWS][128] bf16
    short* H1      = X0 + (size_t)N_ROWS * HID;        // [N_ROWS][128] bf16
    short* Wt1     = H1 + (size_t)N_ROWS * HID;        // [128][640] bf16
    short* Wt2     = Wt1 + HID * KCAT;                 // [128][640] bf16
    float* g       = (float*)(Wt2 + HID * KCAT);       // [512][128] f32
    int*   cnt     = (int*)(g + N_GRAPH * HID);        // SEGP
    int*   off     = cnt + SEGP;                       // SEGP
    int*   tilecnt = off + SEGP;                       // NTILEP
    int*   rawoff  = tilecnt + NTILEP;                 // NTILEP
    int*   obase   = rawoff + NTILEP;                  // NTILEP
    int*   rank    = obase + NTILEP;                   // E
    int2*  ebuf    = (int2*)(rank + N_EDGES);          // E (8B records)
    int*   ssrc    = (int*)(ebuf + N_EDGES);           // SSRC_ALLOC

    // preprocessing (xcvt + weights + zero tilecnt/g)
    k_prep<<<(PREP_TOTAL + 255) / 256, 256, 0, stream>>>(
        x, basis1, comp1, root1, basis2, comp2, root2,
        X0, H1, Wt1, Wt2, tilecnt, g);

    // tile-binned CSR build
    k_tilecnt<<<(N_EDGES + 255) / 256, 256, 0, stream>>>(dst, tilecnt, rank);
    k_tilescan<<<1, 1024, 0, stream>>>(tilecnt, rawoff, obase);
    k_tilescatter<<<(N_EDGES + 255) / 256, 256, 0, stream>>>(et, src, dst, rank, rawoff, ebuf);
    k_tilesort<<<NTILE, 256, 0, stream>>>(ebuf, tilecnt, rawoff, obase, ssrc, off, cnt);

    // layer 1: h1 = relu( [means(x)|x] @ W1stack + bias1 )
    k_fused<1><<<NTILE, 512, 0, stream>>>(X0, off, cnt, ssrc, Wt1, bias1, H1,
                                          nullptr, nullptr);
    // layer 2: pool( [means(h1)|h1] @ W2stack ) fused; bias2 folded into fc
    k_fused<2><<<NTILE, 512, 0, stream>>>(H1, off, cnt, ssrc, Wt2, nullptr, nullptr,
                                          batch, g);

    // fc + log_softmax (with bias2 * node-count fold)
    k_fc<<<N_GRAPH, HID, 0, stream>>>(g, bias2, batch, fcw, fcb, out);
}

// Round 12
// 375.334 us; speedup vs baseline: 1.2044x; 1.2044x over previous
//
#include <hip/hip_runtime.h>
#include <hip/hip_bf16.h>
#include <cstddef>
#include <cstdint>

#define N_NODES 100000
#define N_ROWS  100032            // padded to 32-row tiles
#define DUMMY   100000            // zeroed pad row in feature buffers
#define N_EDGES 1600000
#define N_REL   4
#define N_BASES 30
#define FIN     86
#define HID     128
#define N_CLS   18
#define N_GRAPH 512
#define KCAT    640               // 4 relation blocks + root block, 128 each
#define BM      32                // rows per fused block
#define NKK     (KCAT / 32)       // 20 K-steps

#define SEG (N_REL * N_NODES)                         // 400000 segments (key: node*4+r)
#define SSRC_MAX (N_EDGES + 3 * SEG)                  // padded CSR worst case = 2.8M
#define SSRC_ALLOC (SSRC_MAX + 64)                    // slack
#define SCAN_CHUNK 1024
#define NB_SCAN ((SEG + SCAN_CHUNK - 1) / SCAN_CHUNK) // 391

typedef __attribute__((ext_vector_type(8))) short bf16x8;
typedef __attribute__((ext_vector_type(4))) float f32x4;

__device__ inline float blo(unsigned int u) {
    union { unsigned int i; float f; } c; c.i = u << 16; return c.f;
}
__device__ inline float bhi(unsigned int u) {
    union { unsigned int i; float f; } c; c.i = u & 0xffff0000u; return c.f;
}
__device__ inline unsigned short f2bf(float f) {
    __hip_bfloat16 h = __float2bfloat16(f);
    return *reinterpret_cast<unsigned short*>(&h);
}
__device__ inline unsigned int pk2(float lo, float hi) {
    return (unsigned int)f2bf(lo) | ((unsigned int)f2bf(hi) << 16);
}
__device__ inline int pad4i(int x) { return (x + 3) & ~3; }

// ===== fused preprocessing: xcvt + wt1 + wt2 + ssrc-fill + cnt/g zero =====
#define PREP_R0 (N_ROWS * HID)            // xcvt + H1 pad-row zero
#define PREP_R1 (KCAT * HID)              // wt1
#define PREP_R2 (KCAT * HID)              // wt2
#define PREP_R3 SSRC_ALLOC                // ssrc fill with DUMMY
#define PREP_R4 SEG                       // cnt zero
#define PREP_R5 (N_GRAPH * HID)           // g zero
#define PREP_TOTAL (PREP_R0 + PREP_R1 + PREP_R2 + PREP_R3 + PREP_R4 + PREP_R5)

__device__ inline void wt_body(int id, int KV, const float* __restrict__ basis,
                               const float* __restrict__ comp, const float* __restrict__ root,
                               short* __restrict__ Wt) {
    int n = id & 127, s = id >> 7;
    int k = s & 127, blk = s >> 7;
    float v = 0.f;
    if (k < KV) {
        if (blk < N_REL) {
            for (int b = 0; b < N_BASES; ++b)
                v += comp[blk * N_BASES + b] * basis[((size_t)b * KV + k) * HID + n];
        } else {
            v = root[k * HID + n];
        }
    }
    Wt[(size_t)n * KCAT + s] = (short)f2bf(v);
}

__global__ void k_prep(const float* __restrict__ x,
                       const float* __restrict__ basis1, const float* __restrict__ comp1,
                       const float* __restrict__ root1,
                       const float* __restrict__ basis2, const float* __restrict__ comp2,
                       const float* __restrict__ root2,
                       short* __restrict__ X0, short* __restrict__ H1,
                       short* __restrict__ Wt1, short* __restrict__ Wt2,
                       int* __restrict__ ssrc, int* __restrict__ cnt,
                       float* __restrict__ g) {
    int id = blockIdx.x * 256 + threadIdx.x;
    if (id < PREP_R0) {
        int n = id >> 7, k = id & 127;
        float v = (n < N_NODES && k < FIN) ? x[n * FIN + k] : 0.f;
        X0[id] = (short)f2bf(v);
        if (n >= N_NODES) H1[id] = 0;
        return;
    }
    id -= PREP_R0;
    if (id < PREP_R1) { wt_body(id, FIN, basis1, comp1, root1, Wt1); return; }
    id -= PREP_R1;
    if (id < PREP_R2) { wt_body(id, HID, basis2, comp2, root2, Wt2); return; }
    id -= PREP_R2;
    if (id < PREP_R3) { ssrc[id] = DUMMY; return; }
    id -= PREP_R3;
    if (id < PREP_R4) { cnt[id] = 0; return; }
    id -= PREP_R4;
    if (id < PREP_R5) g[id] = 0.f;
}

// histogram + per-edge rank in one atomic pass (segment key = dst*4 + et,
// 400K counters -> low contention)
__global__ void k_count(const int* __restrict__ et, const int* __restrict__ dst,
                        int* __restrict__ cnt, int* __restrict__ rank) {
    int e = blockIdx.x * 256 + threadIdx.x;
    if (e >= N_EDGES) return;
    rank[e] = atomicAdd(cnt + dst[e] * 4 + et[e], 1);
}

// ---- scan of pad4(cnt[SEG]) -> off[SEG] (all offsets 4-aligned) ----
__global__ void k_bsum(const int* __restrict__ cnt, int* __restrict__ bsum) {
    __shared__ int red[256];
    int base = blockIdx.x * SCAN_CHUNK + threadIdx.x * 4;
    int s = 0;
#pragma unroll
    for (int j = 0; j < 4; j++) { int idx = base + j; if (idx < SEG) s += pad4i(cnt[idx]); }
    red[threadIdx.x] = s;
    __syncthreads();
    for (int w = 128; w > 0; w >>= 1) {
        if (threadIdx.x < w) red[threadIdx.x] += red[threadIdx.x + w];
        __syncthreads();
    }
    if (threadIdx.x == 0) bsum[blockIdx.x] = red[0];
}

// parallel single-block exclusive scan of bsum (NB_SCAN < 512)
__global__ void k_bpref(int* __restrict__ bsum, int nb) {
    __shared__ int s[512];
    int t = threadIdx.x;
    int v = (t < nb) ? bsum[t] : 0;
    s[t] = v;
    __syncthreads();
    for (int d = 1; d < 512; d <<= 1) {
        int add = (t >= d) ? s[t - d] : 0;
        __syncthreads();
        s[t] += add;
        __syncthreads();
    }
    if (t < nb) bsum[t] = s[t] - v;
}

__global__ void k_offsets(const int* __restrict__ cnt, const int* __restrict__ bpref,
                          int* __restrict__ off) {
    __shared__ int tp[256];
    int t = threadIdx.x;
    int base = blockIdx.x * SCAN_CHUNK + t * 4;
    int v[4], s = 0;
#pragma unroll
    for (int j = 0; j < 4; j++) { int idx = base + j; v[j] = (idx < SEG) ? pad4i(cnt[idx]) : 0; s += v[j]; }
    tp[t] = s;
    __syncthreads();
    if (t == 0) { int run = 0; for (int i = 0; i < 256; i++) { int x = tp[i]; tp[i] = run; run += x; } }
    __syncthreads();
    int p = bpref[blockIdx.x] + tp[t];
#pragma unroll
    for (int j = 0; j < 4; j++) { int idx = base + j; if (idx < SEG) off[idx] = p; p += v[j]; }
}

// atomic-free scatter using precomputed rank (pad slots keep DUMMY from prep)
__global__ void k_scatter(const int* __restrict__ et, const int* __restrict__ srcI,
                          const int* __restrict__ dstI, const int* __restrict__ off,
                          const int* __restrict__ rank, int* __restrict__ ssrc) {
    int e = blockIdx.x * 256 + threadIdx.x;
    if (e >= N_EDGES) return;
    int seg = dstI[e] * 4 + et[e];
    ssrc[off[seg] + rank[e]] = srcI[e];
}

// ---- single-relation gather+mean into swizzled LDS A-tile (round-8 core) ----
__device__ __forceinline__ void agg_one(const short* __restrict__ F,
                                        const int4* __restrict__ sp,
                                        int o, int c, int4 e4,
                                        char* Ab, int G, int q, int r) {
    float a[8];
#pragma unroll
    for (int j = 0; j < 8; ++j) a[j] = 0.f;
    const int cq = q * 8;
    const int nch = (c + 3) >> 2;
    const int ib = o >> 2;                      // o is 4-aligned
    for (int ch = 0; ch < nch; ++ch) {
        if (ch) e4 = sp[ib + ch];
        uint4 v0 = *reinterpret_cast<const uint4*>(F + (size_t)e4.x * HID + cq);
        uint4 v1 = *reinterpret_cast<const uint4*>(F + (size_t)e4.y * HID + cq);
        uint4 v2 = *reinterpret_cast<const uint4*>(F + (size_t)e4.z * HID + cq);
        uint4 v3 = *reinterpret_cast<const uint4*>(F + (size_t)e4.w * HID + cq);
        a[0] += blo(v0.x); a[1] += bhi(v0.x); a[2] += blo(v0.y); a[3] += bhi(v0.y);
        a[4] += blo(v0.z); a[5] += bhi(v0.z); a[6] += blo(v0.w); a[7] += bhi(v0.w);
        a[0] += blo(v1.x); a[1] += bhi(v1.x); a[2] += blo(v1.y); a[3] += bhi(v1.y);
        a[4] += blo(v1.z); a[5] += bhi(v1.z); a[6] += blo(v1.w); a[7] += bhi(v1.w);
        a[0] += blo(v2.x); a[1] += bhi(v2.x); a[2] += blo(v2.y); a[3] += bhi(v2.y);
        a[4] += blo(v2.z); a[5] += bhi(v2.z); a[6] += blo(v2.w); a[7] += bhi(v2.w);
        a[0] += blo(v3.x); a[1] += bhi(v3.x); a[2] += blo(v3.y); a[3] += bhi(v3.y);
        a[4] += blo(v3.z); a[5] += bhi(v3.z); a[6] += blo(v3.w); a[7] += bhi(v3.w);
    }
    const float inv = (c > 0) ? 1.f / (float)c : 0.f;
    uint4 w;
    w.x = pk2(a[0] * inv, a[1] * inv);
    w.y = pk2(a[2] * inv, a[3] * inv);
    w.z = pk2(a[4] * inv, a[5] * inv);
    w.w = pk2(a[6] * inv, a[7] * inv);
    const int swz = (G & 7) << 4;
    *reinterpret_cast<uint4*>(Ab + (G * 1280 + ((r * 256 + q * 16) ^ swz))) = w;
}

// ===== fused agg+GEMM: one 32-row M-tile per block, 512 thr (8 waves) =====
template <int MODE>
__launch_bounds__(512, 4)
__global__ void k_fused(const short* __restrict__ F,
                        const int* __restrict__ off, const int* __restrict__ cnt,
                        const int* __restrict__ ssrc,
                        const short* __restrict__ Wt,
                        const float* __restrict__ bias,
                        short* __restrict__ H,
                        const int* __restrict__ batch, float* __restrict__ g) {
    __shared__ short As[BM * KCAT];                 // 40960 B
    char* Ab = reinterpret_cast<char*>(As);
    const int tid = threadIdx.x;
    const int m0 = blockIdx.x * BM;
    const int G = tid >> 4, q = tid & 15;
    const int node = m0 + G;

    // hoisted segment descriptors + chunk-0 prefetch (r0, r1)
    int4 o4 = (int4){0, 0, 0, 0}, c4 = (int4){0, 0, 0, 0};
    const int4* sp = reinterpret_cast<const int4*>(ssrc);
    if (node < N_NODES) {
        o4 = *reinterpret_cast<const int4*>(off + node * 4);
        c4 = *reinterpret_cast<const int4*>(cnt + node * 4);
    }
    int4 pre0 = sp[o4.x >> 2];
    int4 pre1 = sp[o4.y >> 2];

    // ---- phase 1: root block cols [512,640)
    {
        uint4 v = *reinterpret_cast<const uint4*>(F + (size_t)(m0 + G) * HID + q * 8);
        const int p = (G * 1280 + 1024 + q * 16) ^ ((G & 7) << 4);
        *reinterpret_cast<uint4*>(Ab + p) = v;
    }

    // ---- phase 2: relation means cols [0,512)
    if (node < N_NODES) {
        agg_one(F, sp, o4.x, c4.x, pre0, Ab, G, q, 0);
        agg_one(F, sp, o4.y, c4.y, pre1, Ab, G, q, 1);
        agg_one(F, sp, o4.z, c4.z, sp[o4.z >> 2], Ab, G, q, 2);
        agg_one(F, sp, o4.w, c4.w, sp[o4.w >> 2], Ab, G, q, 3);
    }
    __syncthreads();

    // ---- phase 3: MFMA over K=640 (B slice streamed from L2)
    const int wave = tid >> 6, lane = tid & 63;
    const int ql = lane & 15, hi = lane >> 4;
    const int col = wave * 16 + ql;

    bf16x8 bfrag[NKK];
    {
        const short* bp = Wt + (size_t)col * KCAT + hi * 8;
#pragma unroll
        for (int kk = 0; kk < NKK; ++kk)
            bfrag[kk] = *reinterpret_cast<const bf16x8*>(bp + kk * 32);
    }

    f32x4 acc[2];
    acc[0] = (f32x4){0.f, 0.f, 0.f, 0.f};
    acc[1] = (f32x4){0.f, 0.f, 0.f, 0.f};
    const int arow = ql * 1280;
    const int bx = (hi * 16) ^ ((ql & 7) << 4);
#pragma unroll
    for (int kk = 0; kk < NKK; ++kk) {
        const int bo = (kk * 64) ^ bx;
#pragma unroll
        for (int rf = 0; rf < 2; ++rf) {
            bf16x8 a = *reinterpret_cast<const bf16x8*>(Ab + arow + rf * (16 * 1280) + bo);
            acc[rf] = __builtin_amdgcn_mfma_f32_16x16x32_bf16(a, bfrag[kk], acc[rf], 0, 0, 0);
        }
    }

    // ---- epilogue
    if (MODE == 1) {
        const float bc = bias[col];
#pragma unroll
        for (int rf = 0; rf < 2; ++rf) {
#pragma unroll
            for (int r = 0; r < 4; ++r) {
                const int row = m0 + rf * 16 + hi * 4 + r;
                if (row < N_NODES) {
                    float v = fmaxf(acc[rf][r] + bc, 0.f);
                    H[(size_t)row * HID + col] = (short)f2bf(v);
                }
            }
        }
    } else {
        int curb = -1;
        float run = 0.f;
#pragma unroll
        for (int rf = 0; rf < 2; ++rf) {
#pragma unroll
            for (int r = 0; r < 4; ++r) {
                const int row = m0 + rf * 16 + hi * 4 + r;
                if (row < N_NODES) {
                    int b = batch[row];
                    if (b != curb) {
                        if (curb >= 0) atomicAdd(&g[curb * HID + col], run);
                        curb = b; run = 0.f;
                    }
                    run += acc[rf][r];
                }
            }
        }
        if (curb >= 0) atomicAdd(&g[curb * HID + col], run);
    }
}

// per-graph: pooled = g + cnt*bias2; relu(pooled @ fc_w + fc_b) -> log_softmax
__global__ void k_fc(const float* __restrict__ g, const float* __restrict__ bias2,
                     const int* __restrict__ batch, const float* __restrict__ fcw,
                     const float* __restrict__ fcb, float* __restrict__ out) {
    __shared__ float pooled[HID];
    __shared__ float vals[N_CLS];
    __shared__ float s_lse;
    __shared__ int s_cnt;
    int gi = blockIdx.x, t = threadIdx.x;
    if (t == 0) {
        int lo = 0, hi = N_NODES;
        while (lo < hi) { int m = (lo + hi) >> 1; if (batch[m] < gi) lo = m + 1; else hi = m; }
        int lo2 = lo, hi2 = N_NODES;
        while (lo2 < hi2) { int m = (lo2 + hi2) >> 1; if (batch[m] < gi + 1) lo2 = m + 1; else hi2 = m; }
        s_cnt = lo2 - lo;
    }
    __syncthreads();
    pooled[t] = g[gi * HID + t] + (float)s_cnt * bias2[t];
    __syncthreads();
    if (t < N_CLS) {
        float acc = fcb[t];
        for (int k = 0; k < HID; k++) acc = fmaf(pooled[k], fcw[k * N_CLS + t], acc);
        vals[t] = fmaxf(acc, 0.f);
    }
    __syncthreads();
    if (t == 0) {
        float m = vals[0];
        for (int c = 1; c < N_CLS; c++) m = fmaxf(m, vals[c]);
        float ssum = 0.f;
        for (int c = 0; c < N_CLS; c++) ssum += expf(vals[c] - m);
        s_lse = m + logf(ssum);
    }
    __syncthreads();
    if (t < N_CLS) out[gi * N_CLS + t] = vals[t] - s_lse;
}

extern "C" void kernel_launch(void* const* d_in, const int* in_sizes, int n_in,
                              void* d_out, int out_size, void* d_ws, size_t ws_size,
                              hipStream_t stream) {
    const float* x      = (const float*)d_in[0];
    const int*   ei     = (const int*)d_in[1];
    const int*   src    = ei;
    const int*   dst    = ei + N_EDGES;
    const int*   et     = (const int*)d_in[2];
    const int*   batch  = (const int*)d_in[3];
    const float* basis1 = (const float*)d_in[4];
    const float* comp1  = (const float*)d_in[5];
    const float* root1  = (const float*)d_in[6];
    const float* bias1  = (const float*)d_in[7];
    const float* basis2 = (const float*)d_in[8];
    const float* comp2  = (const float*)d_in[9];
    const float* root2  = (const float*)d_in[10];
    const float* bias2  = (const float*)d_in[11];
    const float* fcw    = (const float*)d_in[12];
    const float* fcb    = (const float*)d_in[13];
    float* out = (float*)d_out;

    // workspace layout (~73 MB); all 16B-aligned
    short* X0   = (short*)d_ws;                        // [N_ROWS][128] bf16
    short* H1   = X0 + (size_t)N_ROWS * HID;           // [N_ROWS][128] bf16
    short* Wt1  = H1 + (size_t)N_ROWS * HID;           // [128][640] bf16
    short* Wt2  = Wt1 + HID * KCAT;                    // [128][640] bf16
    float* g    = (float*)(Wt2 + HID * KCAT);          // [512][128] f32
    int*   cnt  = (int*)(g + N_GRAPH * HID);           // SEG (key node*4+r)
    int*   off  = cnt + SEG;                           // SEG (padded offsets)
    int*   bsum = off + SEG;                           // 512
    int*   rank = bsum + 512;                          // E
    int*   ssrc = rank + N_EDGES;                      // SSRC_ALLOC (padded CSR)

    // fused preprocessing (xcvt + weights + ssrc fill + cnt/g zero)
    k_prep<<<(PREP_TOTAL + 255) / 256, 256, 0, stream>>>(
        x, basis1, comp1, root1, basis2, comp2, root2,
        X0, H1, Wt1, Wt2, ssrc, cnt, g);

    // CSR build by (dst, relation): count(+rank) -> padded scan -> scatter
    k_count<<<(N_EDGES + 255) / 256, 256, 0, stream>>>(et, dst, cnt, rank);
    k_bsum<<<NB_SCAN, 256, 0, stream>>>(cnt, bsum);
    k_bpref<<<1, 512, 0, stream>>>(bsum, NB_SCAN);
    k_offsets<<<NB_SCAN, 256, 0, stream>>>(cnt, bsum, off);
    k_scatter<<<(N_EDGES + 255) / 256, 256, 0, stream>>>(et, src, dst, off, rank, ssrc);

    const int FUSED_GRID = N_ROWS / BM;    // 3126

    // layer 1: h1 = relu( [means(x)|x] @ W1stack + bias1 )
    k_fused<1><<<FUSED_GRID, 512, 0, stream>>>(X0, off, cnt, ssrc, Wt1, bias1, H1,
                                               nullptr, nullptr);
    // layer 2: pool( [means(h1)|h1] @ W2stack ) fused; bias2 folded into fc
    k_fused<2><<<FUSED_GRID, 512, 0, stream>>>(H1, off, cnt, ssrc, Wt2, nullptr, nullptr,
                                               batch, g);

    // fc + log_softmax (with bias2 * node-count fold)
    k_fc<<<N_GRAPH, HID, 0, stream>>>(g, bias2, batch, fcw, fcb, out);
}